// Round 14
// baseline (281.878 us; speedup 1.0000x reference)
//
#include <hip/hip_runtime.h>

// GCN 2-layer + pool + head, R29: per-edge op cut + acc1 round-trip deleted + final fused.
// R28 (221us): top-5 = harness 256MiB poison (43us, fixed). Changes:
//   (1) k_grp run-copy: thread r streams its own run brc[s0..s0+rl) -> ebuf[ex..] -
//       deletes seg stamp + per-edge seg/roff/rsrc LDS lookups (~4 LDS ops/edge), seg
//       array gone -> 24.5KB LDS, 6 blocks/CU.
//   (2) acc1 round-trip (12.8MB) deleted: k_csr1 recomputes self-seed g[c]=d*(x@W1)
//       from x + W1 (L2-hot); k_grp stops writing acc1.
//   (3) k_final fused into k_csr2 (R28 ticket pattern: release fence + device atomic;
//       coherent atomicAdd(p,0.0f) reads of pooled). -1 launch.
//   (4) unroll 8 on consumer edge loops (8 outstanding gathers/lane).
//   h[c] = b + dinv[c]*( g[c] + sum_e w_e * g[row_e] ),  g = dinv * (prev @ W)

#define SH 6
#define RB 64
#define KMAX 2048           // N <= 131072 (row packs in 17 bits)
#define KST (KMAX + 1)      // bof row stride
#define TPB 256
#define BCAP 4096           // per-bucket LDS capacity in k_grp (avg bucket ~2047)
#define PT 1024             // k_part threads
#define PB 256              // partition grid (all CUs)
#define NP 4                // scatter passes (frontier = K/NP buckets)
#define ETCAP 12800         // k_part staged-tile capacity (2 x 50KB LDS)
#define GSPAN 16            // k_csr2 pooled LDS graph span

typedef unsigned short ushort_t;
typedef unsigned char u8;
typedef unsigned long long u64;

__device__ __forceinline__ ushort_t f2bf(float v) {
    unsigned u = __float_as_uint(v);
    u += 0x7FFFu + ((u >> 16) & 1u);   // RNE
    return (ushort_t)(u >> 16);
}

__device__ __forceinline__ unsigned quantw(float w) {
    unsigned wq = (unsigned)__float2int_rn(w * 32768.0f);
    return wq > 32767u ? 32767u : wq;
}

// ---------- partition: staged tile + fused hist(->bcnt) + fused scan + NP-pass scatter ----
__global__ __launch_bounds__(PT)
void k_part(const int* __restrict__ row, const int* __restrict__ col,
            const float* __restrict__ ew, unsigned* __restrict__ bcnt,
            unsigned* __restrict__ done, unsigned* __restrict__ bst,
            unsigned* __restrict__ bof, uint2* __restrict__ brc,
            int E, int K, int tile, int KP) {
    __shared__ unsigned lh[KMAX];                // hist (8KB)
    __shared__ unsigned cur[KMAX];               // scatter cursors (8KB)
    __shared__ unsigned wt[PT / 64];
    __shared__ unsigned lastFlag;
    __shared__ unsigned lc[ETCAP];               // staged col (50KB)
    __shared__ unsigned lp[ETCAP];               // staged payload row|wq15 (50KB)
    int tid = threadIdx.x, b = blockIdx.x;
    int e0 = min(b * tile, E), e1 = min(b * tile + tile, E);
    int cnt = e1 - e0;
    unsigned base = (unsigned)e0;
    bool staged = (cnt <= ETCAP);
    for (int i = tid; i < KMAX; i += PT) lh[i] = 0u;
    __syncthreads();
    if (staged) {
        for (int j = tid; j < cnt; j += PT) {    // single read of col/row/ew
            int e = e0 + j;
            int c = col[e];
            lc[j] = (unsigned)c;
            lp[j] = (unsigned)row[e] | (quantw(ew[e]) << 17);
            atomicAdd(&lh[c >> SH], 1u);
        }
    } else {
        for (int e = e0 + tid; e < e1; e += PT) atomicAdd(&lh[col[e] >> SH], 1u);
    }
    __syncthreads();
    for (int i = tid; i < K; i += PT) {          // feed global fine counts
        unsigned c = lh[i];
        if (c) atomicAdd(&bcnt[i], c);
    }
    __syncthreads();                             // all this block's feeds complete
    if (tid == 0) {
        __threadfence();
        lastFlag = (atomicAdd(done, 1u) == (unsigned)(gridDim.x - 1)) ? 1u : 0u;
    }
    __syncthreads();
    if (lastFlag) {                              // last block: global scan bcnt -> bst
        int i0g = tid << 1;
        unsigned g0 = (i0g < K) ? atomicAdd(&bcnt[i0g], 0u) : 0u;       // coherent read
        unsigned g1 = (i0g + 1 < K) ? atomicAdd(&bcnt[i0g + 1], 0u) : 0u;
        unsigned ts = g0 + g1, v = ts;
#pragma unroll
        for (int o = 1; o < 64; o <<= 1) {
            unsigned u = __shfl_up(v, o, 64);
            if ((tid & 63) >= o) v += u;
        }
        if ((tid & 63) == 63) wt[tid >> 6] = v;
        __syncthreads();
        if (tid == 0) {
            unsigned acc = 0;
#pragma unroll
            for (int w = 0; w < PT / 64; w++) { unsigned t = wt[w]; wt[w] = acc; acc += t; }
        }
        __syncthreads();
        unsigned ex = wt[tid >> 6] + (v - ts);
        if (i0g < K) bst[i0g] = ex;
        if (i0g + 1 < K) bst[i0g + 1] = ex + g0;
        __syncthreads();                         // wt free for local scan
    }
    // local exclusive scan of lh (2 serial/thread + wave shfl + wave totals)
    int i0 = tid << 1;
    unsigned a0 = lh[i0], a1 = lh[i0 + 1];
    unsigned ts = a0 + a1, v = ts;
#pragma unroll
    for (int o = 1; o < 64; o <<= 1) {
        unsigned u = __shfl_up(v, o, 64);
        if ((tid & 63) >= o) v += u;
    }
    if ((tid & 63) == 63) wt[tid >> 6] = v;
    __syncthreads();
    if (tid == 0) {
        unsigned acc = 0;
#pragma unroll
        for (int w = 0; w < PT / 64; w++) { unsigned t = wt[w]; wt[w] = acc; acc += t; }
    }
    __syncthreads();
    unsigned ex = wt[tid >> 6] + (v - ts);
    unsigned* bo = bof + (size_t)b * KST;
    cur[i0] = base + ex;          bo[i0] = base + ex;
    cur[i0 + 1] = base + ex + a0; bo[i0 + 1] = base + ex + a0;
    if (tid == PT - 1) bo[KMAX] = base + ex + ts;
    __syncthreads();
    // NP bucket-range passes: open write frontier ~ KP x 64B per block (L2-resident)
    for (int p = 0; p < NP; ++p) {
        int lo = p * KP, hi = min(lo + KP, K);
        if (staged) {
            for (int j = tid; j < cnt; j += PT) {
                unsigned c = lc[j];
                int bkt = (int)(c >> SH);
                if (bkt >= lo && bkt < hi) {
                    unsigned pos = atomicAdd(&cur[bkt], 1u);
                    brc[pos] = make_uint2(lp[j], c);
                }
            }
        } else {
            for (int e = e0 + tid; e < e1; e += PT) {
                int c = col[e];
                int bkt = c >> SH;
                if (bkt >= lo && bkt < hi) {
                    unsigned pos = atomicAdd(&cur[bkt], 1u);
                    brc[pos] = make_uint2((unsigned)row[e] | (quantw(ew[e]) << 17),
                                          (unsigned)c);
                }
            }
        }
        __syncthreads();                         // temporal frontier boundary
    }
}

// ---------- per-bucket: run-copy gather -> group-by-col -> srt + cptr + dinv + g1b ----
__global__ __launch_bounds__(TPB)
void k_grp(const uint2* __restrict__ brc, const unsigned* __restrict__ bof,
           const unsigned* __restrict__ bst, const float* __restrict__ x,
           const float* __restrict__ W1, unsigned* __restrict__ srt,
           unsigned* __restrict__ cptr, float* __restrict__ dinv,
           unsigned* __restrict__ g1b, int N, int E, int K) {
    // bijective XCD-contiguous swizzle (m204): consecutive buckets share an XCD's L2
    int orig = blockIdx.x;
    int q8 = K >> 3, r8 = K & 7;
    int xcd = orig & 7, idx = orig >> 3;
    int k = (xcd < r8 ? xcd * (q8 + 1) : r8 * (q8 + 1) + (xcd - r8) * q8) + idx;
    int node0 = k << SH;

    __shared__ unsigned ebuf[BCAP];          // 16KB (reused as gtmp after scatter)
    __shared__ u8 cbuf[BCAP];                // 4KB
    __shared__ unsigned rsrc[PB];            // run source starts (fallback path)
    __shared__ unsigned roff[PB + 1];        // exclusive prefix of run lengths
    __shared__ unsigned wt4[TPB / 64];
    __shared__ unsigned cnt64[RB], st64[RB], dq[RB];
    __shared__ float dl[RB], lx[RB * 3], lw[48];
    int tid = threadIdx.x;
    unsigned s = bst[k];
    if (tid < RB) { cnt64[tid] = 0u; dq[tid] = 0u; }
    if (tid < 48) lw[tid] = W1[tid];
    int nn = min(RB, N - node0);
    for (int i = tid; i < nn * 3; i += TPB) lx[i] = x[(size_t)node0 * 3 + i];

    // run table: own run from bof columns k, k+1; 256-entry exclusive scan
    unsigned s0r, rl;
    {
        unsigned s0 = bof[(size_t)tid * KST + k];
        unsigned s1 = bof[(size_t)tid * KST + k + 1];
        rsrc[tid] = s0; s0r = s0;
        rl = s1 - s0;
    }
    unsigned v = rl;
#pragma unroll
    for (int o = 1; o < 64; o <<= 1) {
        unsigned u = __shfl_up(v, o, 64);
        if ((tid & 63) >= o) v += u;
    }
    if ((tid & 63) == 63) wt4[tid >> 6] = v;
    __syncthreads();
    if (tid == 0) {
        unsigned acc = 0;
#pragma unroll
        for (int w = 0; w < TPB / 64; w++) { unsigned t = wt4[w]; wt4[w] = acc; acc += t; }
    }
    __syncthreads();
    unsigned ex = wt4[tid >> 6] + (v - rl);
    roff[tid] = ex;
    if (tid == PB - 1) roff[PB] = ex + rl;
    __syncthreads();
    unsigned c = roff[PB];

    bool fits = (c <= (unsigned)BCAP);
    if (fits) {
        for (unsigned j = 0; j < rl; ++j) {          // stream own run (avg 64B)
            uint2 p = brc[s0r + j];
            unsigned cl = p.y & 63u;
            ebuf[ex + j] = p.x; cbuf[ex + j] = (u8)cl;
            atomicAdd(&cnt64[cl], 1u);
            atomicAdd(&dq[cl], p.x >> 17);
        }
        __syncthreads();
        if (tid == 0) {                                  // tiny serial scan of 64
            unsigned acc = 0;
            for (int i = 0; i < RB; i++) { st64[i] = acc; acc += cnt64[i]; cnt64[i] = 0u; }
        }
        __syncthreads();
        for (unsigned j = tid; j < c; j += TPB) {
            unsigned cl = cbuf[j];
            unsigned pos = st64[cl] + atomicAdd(&cnt64[cl], 1u);
            srt[s + pos] = ebuf[j];                      // within-bucket contiguous range
        }
    } else {                                             // 2-pass fallback (rare): bsearch
#define MAP_SRC(j, srcv)                                                       \
        {                                                                      \
            int lo = 0, hi = PB - 1;                                           \
            _Pragma("unroll")                                                  \
            for (int it = 0; it < 8; ++it) {                                   \
                int mid = (lo + hi + 1) >> 1;                                  \
                if (roff[mid] <= (j)) lo = mid; else hi = mid - 1;             \
            }                                                                  \
            (srcv) = rsrc[lo] + ((j) - roff[lo]);                              \
        }
        for (unsigned j = tid; j < c; j += TPB) {
            unsigned src; MAP_SRC(j, src);
            uint2 p = brc[src];
            unsigned cl = p.y & 63u;
            atomicAdd(&cnt64[cl], 1u);
            atomicAdd(&dq[cl], p.x >> 17);
        }
        __syncthreads();
        if (tid == 0) {
            unsigned acc = 0;
            for (int i = 0; i < RB; i++) { st64[i] = acc; acc += cnt64[i]; cnt64[i] = 0u; }
        }
        __syncthreads();
        for (unsigned j = tid; j < c; j += TPB) {
            unsigned src; MAP_SRC(j, src);
            uint2 p = brc[src];
            unsigned cl = p.y & 63u;
            unsigned pos = st64[cl] + atomicAdd(&cnt64[cl], 1u);
            srt[s + pos] = p.x;
        }
#undef MAP_SRC
    }
    __syncthreads();
    if (tid < RB) {
        float d = rsqrtf(1.0f + (float)dq[tid] * (1.0f / 32768.0f));  // self-loop +1
        dl[tid] = d;
        if (tid < nn) {
            dinv[node0 + tid] = d;
            cptr[node0 + tid] = s + st64[tid];
        }
    }
    if (tid == 0 && node0 + nn == N) cptr[N] = (unsigned)E;  // sentinel
    __syncthreads();
    float* gtmp = (float*)ebuf;   // safe: all ebuf reads complete (nn*16 <= BCAP)
    for (int idx2 = tid; idx2 < nn * 16; idx2 += TPB) {
        int n = idx2 >> 4, f = idx2 & 15;
        float vv = dl[n] * (lx[n * 3] * lw[f] + lx[n * 3 + 1] * lw[16 + f] +
                            lx[n * 3 + 2] * lw[32 + f]);
        gtmp[idx2] = vv;
    }
    __syncthreads();
    for (int idx2 = tid; idx2 < nn * 8; idx2 += TPB) {
        int n = idx2 >> 3, qq = idx2 & 7;
        g1b[(size_t)(node0 + n) * 8 + qq] =
            (unsigned)f2bf(gtmp[n * 16 + 2 * qq]) |
            ((unsigned)f2bf(gtmp[n * 16 + 2 * qq + 1]) << 16);
    }
}

// ---------- layer-1 consumer + mid fused: 4 lanes/col, recomputed self-seed ----------
__global__ __launch_bounds__(TPB)
void k_csr1(const unsigned* __restrict__ srt, const unsigned* __restrict__ cptr,
            const uint2* __restrict__ gb2, const float* __restrict__ x,
            const float* __restrict__ W1, const float* __restrict__ dinv,
            const float* __restrict__ b1, const float* __restrict__ W2,
            unsigned* __restrict__ g2b, float* __restrict__ acc2, int N) {
    int t = blockIdx.x * TPB + threadIdx.x;
    int c = t >> 2, f4 = t & 3;
    if (c >= N) return;
    unsigned e = cptr[c], end = cptr[c + 1];
    float s0 = 0.0f, s1 = 0.0f, s2 = 0.0f, s3 = 0.0f;
#pragma unroll 8
    for (; e < end; ++e) {
        unsigned m = srt[e];                         // same addr across 4 lanes -> merged
        float w = (float)(m >> 17) * (1.0f / 32768.0f);
        uint2 u = gb2[(size_t)(m & 0x1FFFFu) * 4 + f4];  // bf16x4, L2-resident table
        s0 = fmaf(w, __uint_as_float(u.x << 16), s0);
        s1 = fmaf(w, __uint_as_float(u.x & 0xFFFF0000u), s1);
        s2 = fmaf(w, __uint_as_float(u.y << 16), s2);
        s3 = fmaf(w, __uint_as_float(u.y & 0xFFFF0000u), s3);
    }
    float d = dinv[c];
    // self-seed g[c] = d*(x[c]@W1), recomputed (was acc1 round-trip)
    float xx0 = x[(size_t)c * 3], xx1 = x[(size_t)c * 3 + 1], xx2 = x[(size_t)c * 3 + 2];
    const float4 w0 = *(const float4*)&W1[4 * f4];
    const float4 w1 = *(const float4*)&W1[16 + 4 * f4];
    const float4 w2 = *(const float4*)&W1[32 + 4 * f4];
    float g0 = d * (xx0 * w0.x + xx1 * w1.x + xx2 * w2.x);
    float g1 = d * (xx0 * w0.y + xx1 * w1.y + xx2 * w2.y);
    float g2 = d * (xx0 * w0.z + xx1 * w1.z + xx2 * w2.z);
    float g3 = d * (xx0 * w0.w + xx1 * w1.w + xx2 * w2.w);
    const float4 bb = *(const float4*)&b1[4 * f4];
    float h[4];
    h[0] = fmaxf(bb.x + d * (g0 + s0), 0.0f);        // == relu(b1 + d*(g[c]+sum))
    h[1] = fmaxf(bb.y + d * (g1 + s1), 0.0f);
    h[2] = fmaxf(bb.z + d * (g2 + s2), 0.0f);
    h[3] = fmaxf(bb.w + d * (g3 + s3), 0.0f);
    // o[f] = sum_kk h_all[kk] * W2[kk][f]  (kk ascending, same order as old k_mid)
    int base = (threadIdx.x & 63) & ~3;              // group's first lane in wave
    float o0 = 0.0f, o1 = 0.0f, o2 = 0.0f, o3 = 0.0f;
#pragma unroll
    for (int kk = 0; kk < 16; ++kk) {
        float hk = __shfl(h[kk & 3], base + (kk >> 2), 64);
        const float4 wv = *(const float4*)&W2[kk * 16 + 4 * f4];
        o0 = fmaf(hk, wv.x, o0);
        o1 = fmaf(hk, wv.y, o1);
        o2 = fmaf(hk, wv.z, o2);
        o3 = fmaf(hk, wv.w, o3);
    }
    float r0 = d * o0, r1 = d * o1, r2 = d * o2, r3 = d * o3;
    *(float4*)&acc2[(size_t)c * 16 + 4 * f4] = make_float4(r0, r1, r2, r3);
    g2b[(size_t)c * 8 + 2 * f4]     = (unsigned)f2bf(r0) | ((unsigned)f2bf(r1) << 16);
    g2b[(size_t)c * 8 + 2 * f4 + 1] = (unsigned)f2bf(r2) | ((unsigned)f2bf(r3) << 16);
}

// ---------- layer-2 consumer + pool + head fused (last-block ticket) ----------
__global__ __launch_bounds__(TPB)
void k_csr2(const unsigned* __restrict__ srt, const unsigned* __restrict__ cptr,
            const uint2* __restrict__ gb2, const float* __restrict__ acc2,
            const float* __restrict__ dinv, const float* __restrict__ b2,
            const int* __restrict__ batch, float* __restrict__ pooled,
            unsigned* __restrict__ done2, const float* __restrict__ Wlin,
            const float* __restrict__ blin, float* __restrict__ out,
            int N, int G) {
    __shared__ float lacc[GSPAN * 16];               // 1KB graph accum
    __shared__ int lb[64];
    __shared__ unsigned lastFlag;
    int tid = threadIdx.x;
    int t = blockIdx.x * TPB + tid;
    int c = t >> 2, f4 = t & 3;
    int c0 = blockIdx.x * 64;
    int ncols = min(64, N - c0);
    if (tid < ncols) lb[tid] = batch[c0 + tid];
    if (tid < GSPAN * 16) lacc[tid] = 0.0f;
    __syncthreads();
    int gmin = lb[0], gmax = lb[ncols - 1];
    bool fits = (gmax - gmin) < GSPAN;

    if (c < N) {
        unsigned e = cptr[c], end = cptr[c + 1];
        float s0 = 0.0f, s1 = 0.0f, s2 = 0.0f, s3 = 0.0f;
#pragma unroll 8
        for (; e < end; ++e) {
            unsigned m = srt[e];
            float w = (float)(m >> 17) * (1.0f / 32768.0f);
            uint2 u = gb2[(size_t)(m & 0x1FFFFu) * 4 + f4];
            s0 = fmaf(w, __uint_as_float(u.x << 16), s0);
            s1 = fmaf(w, __uint_as_float(u.x & 0xFFFF0000u), s1);
            s2 = fmaf(w, __uint_as_float(u.y << 16), s2);
            s3 = fmaf(w, __uint_as_float(u.y & 0xFFFF0000u), s3);
        }
        float d = dinv[c];
        const float4 se = *(const float4*)&acc2[(size_t)c * 16 + 4 * f4];  // self seed
        const float4 bb = *(const float4*)&b2[4 * f4];
        float h0 = fmaxf(bb.x + d * (se.x + s0), 0.0f);  // h2 = relu(b2+d*acc2_final)
        float h1 = fmaxf(bb.y + d * (se.y + s1), 0.0f);
        float h2 = fmaxf(bb.z + d * (se.z + s2), 0.0f);
        float h3 = fmaxf(bb.w + d * (se.w + s3), 0.0f);
        int g = lb[c - c0];
        if (fits) {
            int o = (g - gmin) * 16 + 4 * f4;
            atomicAdd(&lacc[o],     h0);
            atomicAdd(&lacc[o + 1], h1);
            atomicAdd(&lacc[o + 2], h2);
            atomicAdd(&lacc[o + 3], h3);
        } else {
            atomicAdd(&pooled[(size_t)g * 16 + 4 * f4],     h0);
            atomicAdd(&pooled[(size_t)g * 16 + 4 * f4 + 1], h1);
            atomicAdd(&pooled[(size_t)g * 16 + 4 * f4 + 2], h2);
            atomicAdd(&pooled[(size_t)g * 16 + 4 * f4 + 3], h3);
        }
    }
    if (fits) {
        __syncthreads();
        if (tid < GSPAN * 16) {
            int g = gmin + (tid >> 4);
            float v = lacc[tid];
            if (g < G && v != 0.0f) atomicAdd(&pooled[(size_t)g * 16 + (tid & 15)], v);
        }
    }
    __syncthreads();                                 // block's pool atomics complete
    if (tid == 0) {
        __threadfence();
        lastFlag = (atomicAdd(done2, 1u) == (unsigned)(gridDim.x - 1)) ? 1u : 0u;
    }
    __syncthreads();
    if (lastFlag) {                                  // last block: head (G x 7)
        __threadfence();
        for (int g = tid; g < G; g += TPB) {
            float p[16];
#pragma unroll
            for (int f = 0; f < 16; f++)
                p[f] = atomicAdd(&pooled[(size_t)g * 16 + f], 0.0f);  // coherent read
#pragma unroll
            for (int j = 0; j < 7; j++) {
                float v = blin[j];
#pragma unroll
                for (int f = 0; f < 16; f++) v = fmaf(p[f], Wlin[f * 7 + j], v);
                out[(size_t)g * 7 + j] = v;
            }
        }
    }
}

static inline int cdiv_i(long long a, long long b) { return (int)((a + b - 1) / b); }

extern "C" void kernel_launch(void* const* d_in, const int* in_sizes, int n_in,
                              void* d_out, int out_size, void* d_ws, size_t ws_size,
                              hipStream_t stream) {
    const float* x     = (const float*)d_in[0];
    const int*   ei    = (const int*)d_in[1];
    const float* ew    = (const float*)d_in[2];
    const int*   batch = (const int*)d_in[3];
    const float* W1    = (const float*)d_in[4];
    const float* b1    = (const float*)d_in[5];
    const float* W2    = (const float*)d_in[6];
    const float* b2    = (const float*)d_in[7];
    const float* Wlin  = (const float*)d_in[8];
    const float* blin  = (const float*)d_in[9];
    float* out = (float*)d_out;

    const int N = in_sizes[0] / 3;
    const int E = in_sizes[2];
    const int G = out_size / 7;
    const int K = (N + RB - 1) >> SH;            // fine buckets (1563)
    const int tile = cdiv_i(E, PB);
    const int KP = cdiv_i(K, NP);
    const int* row = ei;
    const int* col = ei + E;

    // layout: brc(uint2) | srt | dinv | g1b | g2b | acc2 | cptr | bst | bof
    //       | [zero: bcnt | done | done2 | pooled]
    uint2*    brc    = (uint2*)d_ws;                        // E (8B)
    unsigned* srt    = (unsigned*)(brc + E);                // E
    float*    dinv   = (float*)(srt + E);                   // N
    unsigned* g1b    = (unsigned*)(dinv + N);               // N*8 (bf16 x16)
    unsigned* g2b    = g1b + (size_t)N * 8;                 // N*8
    float*    acc2   = (float*)(g2b + (size_t)N * 8);       // N*16
    unsigned* cptr   = (unsigned*)(acc2 + (size_t)N * 16);  // N+1
    unsigned* bst    = cptr + N + 1;                        // KMAX
    unsigned* bof    = bst + KMAX;                          // PB*KST
    unsigned* bcnt   = bof + (size_t)PB * KST;              // KMAX
    unsigned* done   = bcnt + KMAX;                         // 1
    unsigned* done2  = done + 1;                            // 1
    float*    pooled = (float*)(done2 + 1);                 // G*16

    hipMemsetAsync(bcnt, 0, (KMAX + 2 + (size_t)G * 16) * sizeof(unsigned), stream);

    // CSR build: staged-tile partition (read-once, fused hist + fused scan) -> group
    k_part<<<PB, PT, 0, stream>>>(row, col, ew, bcnt, done, bst, bof, brc,
                                  E, K, tile, KP);
    k_grp<<<K, TPB, 0, stream>>>(brc, bof, bst, x, W1, srt, cptr, dinv, g1b,
                                 N, E, K);

    // layer 1 + mid fused: 4-lane consumer -> g2b + acc2 seed (self-seed recomputed)
    k_csr1<<<cdiv_i((long long)N * 4, TPB), TPB, 0, stream>>>(
        srt, cptr, (const uint2*)g1b, x, W1, dinv, b1, W2, g2b, acc2, N);

    // layer 2 + pool + head fused: 4-lane consumer -> pooled -> out (last block)
    k_csr2<<<cdiv_i((long long)N * 4, TPB), TPB, 0, stream>>>(
        srt, cptr, (const uint2*)g2b, acc2, dinv, b2, batch, pooled,
        done2, Wlin, blin, out, N, G);
}

// Round 15
// 216.703 us; speedup vs baseline: 1.3008x; 1.3008x over previous
//
#include <hip/hip_runtime.h>

// GCN 2-layer + pool + head, R30: exact R28 (best, 221us) + acc1 round-trip deleted.
// R29 post-mortem: head-fusion ticket in k_csr2 cost +58us - per-block __threadfence
// (cross-XCD L2 writeback) + same-address device atomic across 6250 blocks serializes.
// Ticket-fusion is only viable for small grids (k_part's 256-block ticket is fine).
// This round: R28 verbatim EXCEPT (a) k_grp no longer writes acc1 (-6.4MB W);
// (b) k_csr1 recomputes self-seed g[c]=d*(x[c]@W1) from x + L2-hot W1 (-6.4MB R).
// k_final stays a separate launch.
//   h[c] = b + dinv[c]*( g[c] + sum_e w_e * g[row_e] ),  g = dinv * (prev @ W)

#define SH 6
#define RB 64
#define KMAX 2048           // N <= 131072 (row packs in 17 bits)
#define KST (KMAX + 1)      // bof row stride
#define TPB 256
#define BCAP 4096           // per-bucket LDS capacity in k_grp (avg bucket ~2047)
#define PT 1024             // k_part threads
#define PB 256              // partition grid (all CUs)
#define NP 4                // scatter passes (frontier = K/NP buckets)
#define ETCAP 12800         // k_part staged-tile capacity (2 x 50KB LDS)
#define GSPAN 16            // k_csr2 pooled LDS graph span

typedef unsigned short ushort_t;
typedef unsigned char u8;
typedef unsigned long long u64;

__device__ __forceinline__ ushort_t f2bf(float v) {
    unsigned u = __float_as_uint(v);
    u += 0x7FFFu + ((u >> 16) & 1u);   // RNE
    return (ushort_t)(u >> 16);
}

__device__ __forceinline__ unsigned quantw(float w) {
    unsigned wq = (unsigned)__float2int_rn(w * 32768.0f);
    return wq > 32767u ? 32767u : wq;
}

// ---------- partition: staged tile + fused hist(->bcnt) + fused scan + NP-pass scatter ----
__global__ __launch_bounds__(PT)
void k_part(const int* __restrict__ row, const int* __restrict__ col,
            const float* __restrict__ ew, unsigned* __restrict__ bcnt,
            unsigned* __restrict__ done, unsigned* __restrict__ bst,
            unsigned* __restrict__ bof, uint2* __restrict__ brc,
            int E, int K, int tile, int KP) {
    __shared__ unsigned lh[KMAX];                // hist (8KB)
    __shared__ unsigned cur[KMAX];               // scatter cursors (8KB)
    __shared__ unsigned wt[PT / 64];
    __shared__ unsigned lastFlag;
    __shared__ unsigned lc[ETCAP];               // staged col (50KB)
    __shared__ unsigned lp[ETCAP];               // staged payload row|wq15 (50KB)
    int tid = threadIdx.x, b = blockIdx.x;
    int e0 = min(b * tile, E), e1 = min(b * tile + tile, E);
    int cnt = e1 - e0;
    unsigned base = (unsigned)e0;
    bool staged = (cnt <= ETCAP);
    for (int i = tid; i < KMAX; i += PT) lh[i] = 0u;
    __syncthreads();
    if (staged) {
        for (int j = tid; j < cnt; j += PT) {    // single read of col/row/ew
            int e = e0 + j;
            int c = col[e];
            lc[j] = (unsigned)c;
            lp[j] = (unsigned)row[e] | (quantw(ew[e]) << 17);
            atomicAdd(&lh[c >> SH], 1u);
        }
    } else {
        for (int e = e0 + tid; e < e1; e += PT) atomicAdd(&lh[col[e] >> SH], 1u);
    }
    __syncthreads();
    for (int i = tid; i < K; i += PT) {          // feed global fine counts
        unsigned c = lh[i];
        if (c) atomicAdd(&bcnt[i], c);
    }
    __syncthreads();                             // all this block's feeds complete
    if (tid == 0) {
        __threadfence();
        lastFlag = (atomicAdd(done, 1u) == (unsigned)(gridDim.x - 1)) ? 1u : 0u;
    }
    __syncthreads();
    if (lastFlag) {                              // last block: global scan bcnt -> bst
        int i0g = tid << 1;
        unsigned g0 = (i0g < K) ? atomicAdd(&bcnt[i0g], 0u) : 0u;       // coherent read
        unsigned g1 = (i0g + 1 < K) ? atomicAdd(&bcnt[i0g + 1], 0u) : 0u;
        unsigned ts = g0 + g1, v = ts;
#pragma unroll
        for (int o = 1; o < 64; o <<= 1) {
            unsigned u = __shfl_up(v, o, 64);
            if ((tid & 63) >= o) v += u;
        }
        if ((tid & 63) == 63) wt[tid >> 6] = v;
        __syncthreads();
        if (tid == 0) {
            unsigned acc = 0;
#pragma unroll
            for (int w = 0; w < PT / 64; w++) { unsigned t = wt[w]; wt[w] = acc; acc += t; }
        }
        __syncthreads();
        unsigned ex = wt[tid >> 6] + (v - ts);
        if (i0g < K) bst[i0g] = ex;
        if (i0g + 1 < K) bst[i0g + 1] = ex + g0;
        __syncthreads();                         // wt free for local scan
    }
    // local exclusive scan of lh (2 serial/thread + wave shfl + wave totals)
    int i0 = tid << 1;
    unsigned a0 = lh[i0], a1 = lh[i0 + 1];
    unsigned ts = a0 + a1, v = ts;
#pragma unroll
    for (int o = 1; o < 64; o <<= 1) {
        unsigned u = __shfl_up(v, o, 64);
        if ((tid & 63) >= o) v += u;
    }
    if ((tid & 63) == 63) wt[tid >> 6] = v;
    __syncthreads();
    if (tid == 0) {
        unsigned acc = 0;
#pragma unroll
        for (int w = 0; w < PT / 64; w++) { unsigned t = wt[w]; wt[w] = acc; acc += t; }
    }
    __syncthreads();
    unsigned ex = wt[tid >> 6] + (v - ts);
    unsigned* bo = bof + (size_t)b * KST;
    cur[i0] = base + ex;          bo[i0] = base + ex;
    cur[i0 + 1] = base + ex + a0; bo[i0 + 1] = base + ex + a0;
    if (tid == PT - 1) bo[KMAX] = base + ex + ts;
    __syncthreads();
    // NP bucket-range passes: open write frontier ~ KP x 64B per block (L2-resident)
    for (int p = 0; p < NP; ++p) {
        int lo = p * KP, hi = min(lo + KP, K);
        if (staged) {
            for (int j = tid; j < cnt; j += PT) {
                unsigned c = lc[j];
                int bkt = (int)(c >> SH);
                if (bkt >= lo && bkt < hi) {
                    unsigned pos = atomicAdd(&cur[bkt], 1u);
                    brc[pos] = make_uint2(lp[j], c);
                }
            }
        } else {
            for (int e = e0 + tid; e < e1; e += PT) {
                int c = col[e];
                int bkt = c >> SH;
                if (bkt >= lo && bkt < hi) {
                    unsigned pos = atomicAdd(&cur[bkt], 1u);
                    brc[pos] = make_uint2((unsigned)row[e] | (quantw(ew[e]) << 17),
                                          (unsigned)c);
                }
            }
        }
        __syncthreads();                         // temporal frontier boundary
    }
}

// ---------- per-bucket: gather 256 runs -> group-by-col -> srt + cptr + dinv + g1b ----
__global__ __launch_bounds__(TPB)
void k_grp(const uint2* __restrict__ brc, const unsigned* __restrict__ bof,
           const unsigned* __restrict__ bst, const float* __restrict__ x,
           const float* __restrict__ W1, unsigned* __restrict__ srt,
           unsigned* __restrict__ cptr, float* __restrict__ dinv,
           unsigned* __restrict__ g1b, int N, int E, int K) {
    // bijective XCD-contiguous swizzle (m204): consecutive buckets share an XCD's L2
    int orig = blockIdx.x;
    int q8 = K >> 3, r8 = K & 7;
    int xcd = orig & 7, idx = orig >> 3;
    int k = (xcd < r8 ? xcd * (q8 + 1) : r8 * (q8 + 1) + (xcd - r8) * q8) + idx;
    int node0 = k << SH;

    __shared__ unsigned ebuf[BCAP];          // 16KB (reused as gtmp after scatter)
    __shared__ u8 cbuf[BCAP];                // 4KB
    __shared__ u8 seg[BCAP];                 // 4KB: j -> run id
    __shared__ unsigned rsrc[PB];            // run source starts
    __shared__ unsigned roff[PB + 1];        // exclusive prefix of run lengths
    __shared__ unsigned wt4[TPB / 64];
    __shared__ unsigned cnt64[RB], st64[RB], dq[RB];
    __shared__ float dl[RB], lx[RB * 3], lw[48];
    int tid = threadIdx.x;
    unsigned s = bst[k];
    if (tid < RB) { cnt64[tid] = 0u; dq[tid] = 0u; }
    if (tid < 48) lw[tid] = W1[tid];
    int nn = min(RB, N - node0);
    for (int i = tid; i < nn * 3; i += TPB) lx[i] = x[(size_t)node0 * 3 + i];

    // run table: rsrc/len from bof columns k, k+1; 256-entry exclusive scan
    unsigned rl;
    {
        unsigned s0 = bof[(size_t)tid * KST + k];
        unsigned s1 = bof[(size_t)tid * KST + k + 1];
        rsrc[tid] = s0;
        rl = s1 - s0;
    }
    unsigned v = rl;
#pragma unroll
    for (int o = 1; o < 64; o <<= 1) {
        unsigned u = __shfl_up(v, o, 64);
        if ((tid & 63) >= o) v += u;
    }
    if ((tid & 63) == 63) wt4[tid >> 6] = v;
    __syncthreads();
    if (tid == 0) {
        unsigned acc = 0;
#pragma unroll
        for (int w = 0; w < TPB / 64; w++) { unsigned t = wt4[w]; wt4[w] = acc; acc += t; }
    }
    __syncthreads();
    unsigned ex = wt4[tid >> 6] + (v - rl);
    roff[tid] = ex;
    if (tid == PB - 1) roff[PB] = ex + rl;
    __syncthreads();
    unsigned c = roff[PB];

    bool fits = (c <= (unsigned)BCAP);
    if (fits) {
        for (unsigned j = ex; j < ex + rl; ++j) seg[j] = (u8)tid;  // stamp run ids
        __syncthreads();
        for (unsigned j = tid; j < c; j += TPB) {
            unsigned r = seg[j];
            unsigned src = rsrc[r] + (j - roff[r]);
            uint2 p = brc[src];
            unsigned cl = p.y & 63u;
            ebuf[j] = p.x; cbuf[j] = (u8)cl;
            atomicAdd(&cnt64[cl], 1u);
            atomicAdd(&dq[cl], p.x >> 17);
        }
        __syncthreads();
        if (tid == 0) {                                  // tiny serial scan of 64
            unsigned acc = 0;
            for (int i = 0; i < RB; i++) { st64[i] = acc; acc += cnt64[i]; cnt64[i] = 0u; }
        }
        __syncthreads();
        for (unsigned j = tid; j < c; j += TPB) {
            unsigned cl = cbuf[j];
            unsigned pos = st64[cl] + atomicAdd(&cnt64[cl], 1u);
            srt[s + pos] = ebuf[j];                      // within-bucket contiguous range
        }
    } else {                                             // 2-pass fallback (rare): bsearch
#define MAP_SRC(j, srcv)                                                       \
        {                                                                      \
            int lo = 0, hi = PB - 1;                                           \
            _Pragma("unroll")                                                  \
            for (int it = 0; it < 8; ++it) {                                   \
                int mid = (lo + hi + 1) >> 1;                                  \
                if (roff[mid] <= (j)) lo = mid; else hi = mid - 1;             \
            }                                                                  \
            (srcv) = rsrc[lo] + ((j) - roff[lo]);                              \
        }
        for (unsigned j = tid; j < c; j += TPB) {
            unsigned src; MAP_SRC(j, src);
            uint2 p = brc[src];
            unsigned cl = p.y & 63u;
            atomicAdd(&cnt64[cl], 1u);
            atomicAdd(&dq[cl], p.x >> 17);
        }
        __syncthreads();
        if (tid == 0) {
            unsigned acc = 0;
            for (int i = 0; i < RB; i++) { st64[i] = acc; acc += cnt64[i]; cnt64[i] = 0u; }
        }
        __syncthreads();
        for (unsigned j = tid; j < c; j += TPB) {
            unsigned src; MAP_SRC(j, src);
            uint2 p = brc[src];
            unsigned cl = p.y & 63u;
            unsigned pos = st64[cl] + atomicAdd(&cnt64[cl], 1u);
            srt[s + pos] = p.x;
        }
#undef MAP_SRC
    }
    __syncthreads();
    if (tid < RB) {
        float d = rsqrtf(1.0f + (float)dq[tid] * (1.0f / 32768.0f));  // self-loop +1
        dl[tid] = d;
        if (tid < nn) {
            dinv[node0 + tid] = d;
            cptr[node0 + tid] = s + st64[tid];
        }
    }
    if (tid == 0 && node0 + nn == N) cptr[N] = (unsigned)E;  // sentinel
    __syncthreads();
    float* gtmp = (float*)ebuf;   // safe: all ebuf reads complete (nn*16 <= BCAP)
    for (int idx2 = tid; idx2 < nn * 16; idx2 += TPB) {
        int n = idx2 >> 4, f = idx2 & 15;
        float vv = dl[n] * (lx[n * 3] * lw[f] + lx[n * 3 + 1] * lw[16 + f] +
                            lx[n * 3 + 2] * lw[32 + f]);
        gtmp[idx2] = vv;                         // acc1 write deleted (seed recomputed)
    }
    __syncthreads();
    for (int idx2 = tid; idx2 < nn * 8; idx2 += TPB) {
        int n = idx2 >> 3, qq = idx2 & 7;
        g1b[(size_t)(node0 + n) * 8 + qq] =
            (unsigned)f2bf(gtmp[n * 16 + 2 * qq]) |
            ((unsigned)f2bf(gtmp[n * 16 + 2 * qq + 1]) << 16);
    }
}

// ---------- layer-1 consumer + mid fused: 4 lanes/col, recomputed self-seed ----------
__global__ __launch_bounds__(TPB)
void k_csr1(const unsigned* __restrict__ srt, const unsigned* __restrict__ cptr,
            const uint2* __restrict__ gb2, const float* __restrict__ x,
            const float* __restrict__ W1, const float* __restrict__ dinv,
            const float* __restrict__ b1, const float* __restrict__ W2,
            unsigned* __restrict__ g2b, float* __restrict__ acc2, int N) {
    int t = blockIdx.x * TPB + threadIdx.x;
    int c = t >> 2, f4 = t & 3;
    if (c >= N) return;
    unsigned e = cptr[c], end = cptr[c + 1];
    float s0 = 0.0f, s1 = 0.0f, s2 = 0.0f, s3 = 0.0f;
#pragma unroll 4
    for (; e < end; ++e) {
        unsigned m = srt[e];                         // same addr across 4 lanes -> merged
        float w = (float)(m >> 17) * (1.0f / 32768.0f);
        uint2 u = gb2[(size_t)(m & 0x1FFFFu) * 4 + f4];  // bf16x4, L2-resident table
        s0 = fmaf(w, __uint_as_float(u.x << 16), s0);
        s1 = fmaf(w, __uint_as_float(u.x & 0xFFFF0000u), s1);
        s2 = fmaf(w, __uint_as_float(u.y << 16), s2);
        s3 = fmaf(w, __uint_as_float(u.y & 0xFFFF0000u), s3);
    }
    float d = dinv[c];
    // self-seed g[c] = d*(x[c]@W1), recomputed (acc1 round-trip deleted)
    float xx0 = x[(size_t)c * 3], xx1 = x[(size_t)c * 3 + 1], xx2 = x[(size_t)c * 3 + 2];
    const float4 w0 = *(const float4*)&W1[4 * f4];
    const float4 w1 = *(const float4*)&W1[16 + 4 * f4];
    const float4 w2 = *(const float4*)&W1[32 + 4 * f4];
    float g0 = d * (xx0 * w0.x + xx1 * w1.x + xx2 * w2.x);
    float g1 = d * (xx0 * w0.y + xx1 * w1.y + xx2 * w2.y);
    float g2 = d * (xx0 * w0.z + xx1 * w1.z + xx2 * w2.z);
    float g3 = d * (xx0 * w0.w + xx1 * w1.w + xx2 * w2.w);
    const float4 bb = *(const float4*)&b1[4 * f4];
    float h[4];
    h[0] = fmaxf(bb.x + d * (g0 + s0), 0.0f);        // == relu(b1 + d*(g[c]+sum))
    h[1] = fmaxf(bb.y + d * (g1 + s1), 0.0f);
    h[2] = fmaxf(bb.z + d * (g2 + s2), 0.0f);
    h[3] = fmaxf(bb.w + d * (g3 + s3), 0.0f);
    // o[f] = sum_kk h_all[kk] * W2[kk][f]  (kk ascending, same order as old k_mid)
    int base = (threadIdx.x & 63) & ~3;              // group's first lane in wave
    float o0 = 0.0f, o1 = 0.0f, o2 = 0.0f, o3 = 0.0f;
#pragma unroll
    for (int kk = 0; kk < 16; ++kk) {
        float hk = __shfl(h[kk & 3], base + (kk >> 2), 64);
        const float4 wv = *(const float4*)&W2[kk * 16 + 4 * f4];
        o0 = fmaf(hk, wv.x, o0);
        o1 = fmaf(hk, wv.y, o1);
        o2 = fmaf(hk, wv.z, o2);
        o3 = fmaf(hk, wv.w, o3);
    }
    float r0 = d * o0, r1 = d * o1, r2 = d * o2, r3 = d * o3;
    *(float4*)&acc2[(size_t)c * 16 + 4 * f4] = make_float4(r0, r1, r2, r3);
    g2b[(size_t)c * 8 + 2 * f4]     = (unsigned)f2bf(r0) | ((unsigned)f2bf(r1) << 16);
    g2b[(size_t)c * 8 + 2 * f4 + 1] = (unsigned)f2bf(r2) | ((unsigned)f2bf(r3) << 16);
}

// ---------- layer-2 consumer + pool fused: 4 lanes/col, sorted-batch LDS pool ----------
__global__ __launch_bounds__(TPB)
void k_csr2(const unsigned* __restrict__ srt, const unsigned* __restrict__ cptr,
            const uint2* __restrict__ gb2, const float* __restrict__ acc2,
            const float* __restrict__ dinv, const float* __restrict__ b2,
            const int* __restrict__ batch, float* __restrict__ pooled,
            int N, int G) {
    __shared__ float lacc[GSPAN * 16];               // 1KB graph accum
    __shared__ int lb[64];
    int tid = threadIdx.x;
    int t = blockIdx.x * TPB + tid;
    int c = t >> 2, f4 = t & 3;
    int c0 = blockIdx.x * 64;
    int ncols = min(64, N - c0);
    if (tid < ncols) lb[tid] = batch[c0 + tid];
    if (tid < GSPAN * 16) lacc[tid] = 0.0f;
    __syncthreads();
    int gmin = lb[0], gmax = lb[ncols - 1];
    bool fits = (gmax - gmin) < GSPAN;

    if (c < N) {
        unsigned e = cptr[c], end = cptr[c + 1];
        float s0 = 0.0f, s1 = 0.0f, s2 = 0.0f, s3 = 0.0f;
#pragma unroll 4
        for (; e < end; ++e) {
            unsigned m = srt[e];
            float w = (float)(m >> 17) * (1.0f / 32768.0f);
            uint2 u = gb2[(size_t)(m & 0x1FFFFu) * 4 + f4];
            s0 = fmaf(w, __uint_as_float(u.x << 16), s0);
            s1 = fmaf(w, __uint_as_float(u.x & 0xFFFF0000u), s1);
            s2 = fmaf(w, __uint_as_float(u.y << 16), s2);
            s3 = fmaf(w, __uint_as_float(u.y & 0xFFFF0000u), s3);
        }
        float d = dinv[c];
        const float4 se = *(const float4*)&acc2[(size_t)c * 16 + 4 * f4];  // self seed
        const float4 bb = *(const float4*)&b2[4 * f4];
        float h0 = fmaxf(bb.x + d * (se.x + s0), 0.0f);  // h2 = relu(b2+d*acc2_final)
        float h1 = fmaxf(bb.y + d * (se.y + s1), 0.0f);
        float h2 = fmaxf(bb.z + d * (se.z + s2), 0.0f);
        float h3 = fmaxf(bb.w + d * (se.w + s3), 0.0f);
        int g = lb[c - c0];
        if (fits) {
            int o = (g - gmin) * 16 + 4 * f4;
            atomicAdd(&lacc[o],     h0);
            atomicAdd(&lacc[o + 1], h1);
            atomicAdd(&lacc[o + 2], h2);
            atomicAdd(&lacc[o + 3], h3);
        } else {
            atomicAdd(&pooled[(size_t)g * 16 + 4 * f4],     h0);
            atomicAdd(&pooled[(size_t)g * 16 + 4 * f4 + 1], h1);
            atomicAdd(&pooled[(size_t)g * 16 + 4 * f4 + 2], h2);
            atomicAdd(&pooled[(size_t)g * 16 + 4 * f4 + 3], h3);
        }
    }
    if (fits) {
        __syncthreads();
        if (tid < GSPAN * 16) {
            int g = gmin + (tid >> 4);
            float v = lacc[tid];
            if (g < G && v != 0.0f) atomicAdd(&pooled[(size_t)g * 16 + (tid & 15)], v);
        }
    }
}

__global__ void k_final(const float* __restrict__ pooled, const float* __restrict__ Wlin,
                        const float* __restrict__ blin, float* __restrict__ out, int G) {
    int t = blockIdx.x * blockDim.x + threadIdx.x;
    int g = t / 7, j = t % 7;
    if (g >= G) return;
    float v = blin[j];
#pragma unroll
    for (int f = 0; f < 16; f++) v += pooled[g * 16 + f] * Wlin[f * 7 + j];
    out[g * 7 + j] = v;
}

static inline int cdiv_i(long long a, long long b) { return (int)((a + b - 1) / b); }

extern "C" void kernel_launch(void* const* d_in, const int* in_sizes, int n_in,
                              void* d_out, int out_size, void* d_ws, size_t ws_size,
                              hipStream_t stream) {
    const float* x     = (const float*)d_in[0];
    const int*   ei    = (const int*)d_in[1];
    const float* ew    = (const float*)d_in[2];
    const int*   batch = (const int*)d_in[3];
    const float* W1    = (const float*)d_in[4];
    const float* b1    = (const float*)d_in[5];
    const float* W2    = (const float*)d_in[6];
    const float* b2    = (const float*)d_in[7];
    const float* Wlin  = (const float*)d_in[8];
    const float* blin  = (const float*)d_in[9];
    float* out = (float*)d_out;

    const int N = in_sizes[0] / 3;
    const int E = in_sizes[2];
    const int G = out_size / 7;
    const int K = (N + RB - 1) >> SH;            // fine buckets (1563)
    const int tile = cdiv_i(E, PB);
    const int KP = cdiv_i(K, NP);
    const int* row = ei;
    const int* col = ei + E;

    // layout: brc(uint2) | srt | dinv | g1b | g2b | acc2 | cptr | bst | bof
    //       | [zero: bcnt | done | pooled]
    uint2*    brc    = (uint2*)d_ws;                        // E (8B)
    unsigned* srt    = (unsigned*)(brc + E);                // E
    float*    dinv   = (float*)(srt + E);                   // N
    unsigned* g1b    = (unsigned*)(dinv + N);               // N*8 (bf16 x16)
    unsigned* g2b    = g1b + (size_t)N * 8;                 // N*8
    float*    acc2   = (float*)(g2b + (size_t)N * 8);       // N*16
    unsigned* cptr   = (unsigned*)(acc2 + (size_t)N * 16);  // N+1
    unsigned* bst    = cptr + N + 1;                        // KMAX
    unsigned* bof    = bst + KMAX;                          // PB*KST
    unsigned* bcnt   = bof + (size_t)PB * KST;              // KMAX
    unsigned* done   = bcnt + KMAX;                         // 1
    float*    pooled = (float*)(done + 1);                  // G*16

    hipMemsetAsync(bcnt, 0, (KMAX + 1 + (size_t)G * 16) * sizeof(unsigned), stream);

    // CSR build: staged-tile partition (read-once, fused hist + fused scan) -> group
    k_part<<<PB, PT, 0, stream>>>(row, col, ew, bcnt, done, bst, bof, brc,
                                  E, K, tile, KP);
    k_grp<<<K, TPB, 0, stream>>>(brc, bof, bst, x, W1, srt, cptr, dinv, g1b,
                                 N, E, K);

    // layer 1 + mid fused: 4-lane consumer -> g2b + acc2 seed (self-seed recomputed)
    k_csr1<<<cdiv_i((long long)N * 4, TPB), TPB, 0, stream>>>(
        srt, cptr, (const uint2*)g1b, x, W1, dinv, b1, W2, g2b, acc2, N);

    // layer 2 + pool fused: 4-lane consumer -> pooled
    k_csr2<<<cdiv_i((long long)N * 4, TPB), TPB, 0, stream>>>(
        srt, cptr, (const uint2*)g2b, acc2, dinv, b2, batch, pooled, N, G);

    // head
    k_final<<<cdiv_i((long long)G * 7, TPB), TPB, 0, stream>>>(pooled, Wlin, blin, out, G);
}